// Round 1
// baseline (375.107 us; speedup 1.0000x reference)
//
#include <hip/hip_runtime.h>
#include <cstdint>
#include <cstddef>

// DenseGAT, N=4096, IN_DIM=256, H=4, D=64, NEG_SLOPE=0.2
//
// Math: w[i,j,h] = exp(leaky_relu(ei+ej) + bias) masked to 0 where bias==0.
//   exp(lrelu(x)+b) = exp(b) * (t>1 ? t^5 : t), t = exp(0.2*ei)*exp(0.2*ej).
// Scores are bounded (|e| <~ 7) so no max-subtraction needed in fp32.
// out[i,h,:] = elu( (sum_j w * Wh[j,h,:]) / (sum_j w) ), fallback to
// elu(Wh[i,h,:]) if the whole row is masked (matches reference self-loop).

// ---------------- Kernel 1: Wh = h @ W  (4096x256 @ 256x256, fp32) --------
__global__ __launch_bounds__(256) void gemm_wh(const float* __restrict__ A,
                                               const float* __restrict__ Bw,
                                               float* __restrict__ C) {
  __shared__ float sA[16][68];   // [kk][row]
  __shared__ float sB[16][68];   // [kk][col]
  const int bx = blockIdx.x;     // col tile (0..3)
  const int by = blockIdx.y;     // row tile (0..63)
  const int t  = threadIdx.x;
  const int tc = t & 15;
  const int tr = t >> 4;
  const int row0 = by * 64, col0 = bx * 64;
  float acc[4][4];
  for (int q = 0; q < 4; q++)
    for (int p = 0; p < 4; p++) acc[q][p] = 0.f;
  for (int k0 = 0; k0 < 256; k0 += 16) {
    __syncthreads();
    {
      const int kk = t & 15, r = t >> 4;        // A: 64 rows x 16 k
      #pragma unroll
      for (int p = 0; p < 4; p++)
        sA[kk][r + p * 16] = A[(size_t)(row0 + r + p * 16) * 256 + k0 + kk];
      const int cc = t & 63, kb = t >> 6;       // B: 16 k x 64 cols
      #pragma unroll
      for (int p = 0; p < 4; p++)
        sB[kb + p * 4][cc] = Bw[(size_t)(k0 + kb + p * 4) * 256 + col0 + cc];
    }
    __syncthreads();
    #pragma unroll
    for (int kk = 0; kk < 16; kk++) {
      float4 av = *(const float4*)&sA[kk][tr * 4];
      float4 bv = *(const float4*)&sB[kk][tc * 4];
      const float aq[4] = {av.x, av.y, av.z, av.w};
      const float bp[4] = {bv.x, bv.y, bv.z, bv.w};
      #pragma unroll
      for (int q = 0; q < 4; q++)
        #pragma unroll
        for (int p = 0; p < 4; p++) acc[q][p] = fmaf(aq[q], bp[p], acc[q][p]);
    }
  }
  #pragma unroll
  for (int q = 0; q < 4; q++) {
    float4 v = make_float4(acc[q][0], acc[q][1], acc[q][2], acc[q][3]);
    *(float4*)&C[(size_t)(row0 + tr * 4 + q) * 256 + col0 + tc * 4] = v;
  }
}

// ---------------- Kernel 2: u_i = exp(0.2*ei), u_j = exp(0.2*ej) ----------
__global__ __launch_bounds__(256) void calc_uij(const float* __restrict__ Wh,
                                                const float* __restrict__ a,
                                                float* __restrict__ ui,
                                                float* __restrict__ uj) {
  const int lane = threadIdx.x & 63;
  const int n = blockIdx.x * 4 + (threadIdx.x >> 6);
  #pragma unroll
  for (int h = 0; h < 4; h++) {
    float v = Wh[(size_t)n * 256 + h * 64 + lane];
    float pi = v * a[h * 128 + lane];
    float pj = v * a[h * 128 + 64 + lane];
    #pragma unroll
    for (int m = 32; m >= 1; m >>= 1) {
      pi += __shfl_xor(pi, m, 64);
      pj += __shfl_xor(pj, m, 64);
    }
    if (lane == 0) {
      ui[n * 4 + h] = __expf(0.2f * pi);
      uj[n * 4 + h] = __expf(0.2f * pj);
    }
  }
}

// ---------------- Kernel 3: fused masked-softmax attention ----------------
// grid (64 i-tiles, chunks j-chunks), block 256 = 4 waves (wave = head).
// lane = row i within the 64-row tile; acc[d] over d=0..63 per lane.
// Partials: P[((c*4+h)*64 + d)*4096 + i]  (lane-coalesced stores)
//           L[(c*4+h)*4096 + i]
__global__ __launch_bounds__(256) void gat_attn(const float* __restrict__ bias,
                                                const float* __restrict__ Wh,
                                                const float* __restrict__ ui,
                                                const float* __restrict__ uj,
                                                float* __restrict__ P,
                                                float* __restrict__ L,
                                                int jpc) {
  __shared__ float sB[64 * 65];      // exp(bias) tile, [jj][ii], padded
  const int itile = blockIdx.x;
  const int c = blockIdx.y;
  const int lane = threadIdx.x & 63;
  const int h = __builtin_amdgcn_readfirstlane(threadIdx.x >> 6);
  const int i0 = itile * 64;
  const int j0 = c * jpc;
  float acc[64];
  #pragma unroll
  for (int d = 0; d < 64; d++) acc[d] = 0.f;
  float l = 0.f;
  const float uiv = ui[(size_t)(i0 + lane) * 4 + h];
  const float* __restrict__ Vh = Wh + h * 64;
  for (int jt = j0; jt < j0 + jpc; jt += 64) {
    __syncthreads();
    {
      const int jj = threadIdx.x & 63;
      const int ib = threadIdx.x >> 6;
      #pragma unroll
      for (int k = 0; k < 16; k++) {
        const int ii = ib + k * 4;
        float g = bias[(size_t)(i0 + ii) * 4096 + jt + jj];
        sB[jj * 65 + ii] = (g == 0.0f) ? 0.0f : __expf(g);
      }
    }
    __syncthreads();
    for (int jj = 0; jj < 64; jj++) {
      const int j = jt + jj;
      const float ujv = uj[j * 4 + h];        // wave-uniform -> s_load
      float tt = uiv * ujv;
      float t2 = tt * tt;
      float t5 = t2 * t2 * tt;
      float w = (tt > 1.0f) ? t5 : tt;        // exp(leaky_relu(ei+ej))
      w *= sB[jj * 65 + lane];                // * exp(bias), 0 if masked
      l += w;
      const float* __restrict__ V = Vh + (size_t)j * 256;  // wave-uniform
      #pragma unroll
      for (int d = 0; d < 64; d++) acc[d] = fmaf(w, V[d], acc[d]);
    }
  }
  const size_t pb = ((size_t)(c * 4 + h) * 64) * 4096 + i0 + lane;
  #pragma unroll
  for (int d = 0; d < 64; d++) P[pb + (size_t)d * 4096] = acc[d];
  L[(size_t)(c * 4 + h) * 4096 + i0 + lane] = l;
}

// ---------------- Kernel 4: reduce partials, normalize, ELU ---------------
// grid (64 i-tiles, 4 heads), block 256.
__global__ __launch_bounds__(256) void reduce_out(const float* __restrict__ P,
                                                  const float* __restrict__ L,
                                                  const float* __restrict__ Wh,
                                                  float* __restrict__ out,
                                                  int chunks) {
  __shared__ float sT[64 * 65];
  const int i0 = blockIdx.x * 64;
  const int h = blockIdx.y;
  const int t = threadIdx.x;
  const int il = t & 63;
  const int dg = t >> 6;     // 0..3, 16 d's each
  float lsum = 0.f;
  for (int c = 0; c < chunks; c++)
    lsum += L[(size_t)(c * 4 + h) * 4096 + i0 + il];
  float s[16];
  #pragma unroll
  for (int q = 0; q < 16; q++) s[q] = 0.f;
  for (int c = 0; c < chunks; c++) {
    const size_t base = ((size_t)(c * 4 + h) * 64) * 4096 + i0 + il;
    #pragma unroll
    for (int q = 0; q < 16; q++) s[q] += P[base + (size_t)(dg * 16 + q) * 4096];
  }
  const bool fb = (lsum == 0.0f);              // fully-masked row fallback
  const float inv = fb ? 0.f : (1.0f / lsum);
  #pragma unroll
  for (int q = 0; q < 16; q++) {
    const int d = dg * 16 + q;
    float o = fb ? Wh[(size_t)(i0 + il) * 256 + h * 64 + d] : s[q] * inv;
    o = (o > 0.f) ? o : (__expf(o) - 1.0f);    // ELU
    sT[d * 65 + il] = o;
  }
  __syncthreads();
  const int d = t & 63;
  const int ib = t >> 6;
  #pragma unroll
  for (int k = 0; k < 16; k++) {
    const int ii = ib + k * 4;
    out[(size_t)(i0 + ii) * 256 + h * 64 + d] = sT[d * 65 + ii];
  }
}

extern "C" void kernel_launch(void* const* d_in, const int* in_sizes, int n_in,
                              void* d_out, int out_size, void* d_ws, size_t ws_size,
                              hipStream_t stream) {
  const float* h_in = (const float*)d_in[0];   // (4096, 256)
  const float* adj  = (const float*)d_in[1];   // (4096, 4096)
  const float* W    = (const float*)d_in[2];   // (256, 256)
  const float* a    = (const float*)d_in[3];   // (4, 128)
  float* out = (float*)d_out;                  // (4096, 256) fp32
  float* ws = (float*)d_ws;

  float* Wh = ws;                       // 1,048,576 floats (4 MB)
  float* ui = ws + 1048576;             // 16,384
  float* uj = ui + 16384;               // 16,384
  float* Lb = uj + 16384;

  int chunks = 8;
  while (chunks > 1) {
    size_t need = (size_t)(1048576 + 32768 +
                           (size_t)chunks * (16384 + 1048576)) * 4;
    if (need <= ws_size) break;
    chunks >>= 1;
  }
  float* Pb = Lb + (size_t)chunks * 16384;
  const int jpc = 4096 / chunks;

  hipLaunchKernelGGL(gemm_wh, dim3(4, 64), dim3(256), 0, stream, h_in, W, Wh);
  hipLaunchKernelGGL(calc_uij, dim3(1024), dim3(256), 0, stream, Wh, a, ui, uj);
  hipLaunchKernelGGL(gat_attn, dim3(64, chunks), dim3(256), 0, stream,
                     adj, Wh, ui, uj, Pb, Lb, jpc);
  hipLaunchKernelGGL(reduce_out, dim3(64, 4), dim3(256), 0, stream,
                     Pb, Lb, Wh, out, chunks);
}

// Round 2
// 194.834 us; speedup vs baseline: 1.9253x; 1.9253x over previous
//
#include <hip/hip_runtime.h>
#include <cstdint>
#include <cstddef>

// DenseGAT, N=4096, IN_DIM=256, H=4, D=64, NEG_SLOPE=0.2
// w[i,j,h] = exp(lrelu(ei+ej)+bias) = eb * (tt>1 ? tt^5 : tt),
//   tt = exp(.2 ei) exp(.2 ej), eb = exp(bias) (0 where masked).
// PV via mfma_f32_16x16x32_f16: A = w (generated in-register in A-frag
// layout), B = Vt (pre-transposed fp16 Wh, B^T pattern). fp32 accum.

typedef _Float16 f16x8 __attribute__((ext_vector_type(8)));
typedef float f32x4 __attribute__((ext_vector_type(4)));

#define NN 4096

// ---------------- Kernel 1: Wh = h @ W  + fp16 transpose Vt ----------------
__global__ __launch_bounds__(256) void gemm_wh(const float* __restrict__ A,
                                               const float* __restrict__ Bw,
                                               float* __restrict__ C,
                                               _Float16* __restrict__ Vt) {
  __shared__ float sA[16][68];   // [kk][row]
  __shared__ float sB[16][68];   // [kk][col]
  __shared__ _Float16 sT[64][68];
  const int bx = blockIdx.x;     // col tile (= head h)
  const int by = blockIdx.y;     // row tile
  const int t  = threadIdx.x;
  const int tc = t & 15;
  const int tr = t >> 4;
  const int row0 = by * 64, col0 = bx * 64;
  float acc[4][4];
  for (int q = 0; q < 4; q++)
    for (int p = 0; p < 4; p++) acc[q][p] = 0.f;
  for (int k0 = 0; k0 < 256; k0 += 16) {
    __syncthreads();
    {
      const int kk = t & 15, r = t >> 4;
      #pragma unroll
      for (int p = 0; p < 4; p++)
        sA[kk][r + p * 16] = A[(size_t)(row0 + r + p * 16) * 256 + k0 + kk];
      const int cc = t & 63, kb = t >> 6;
      #pragma unroll
      for (int p = 0; p < 4; p++)
        sB[kb + p * 4][cc] = Bw[(size_t)(k0 + kb + p * 4) * 256 + col0 + cc];
    }
    __syncthreads();
    #pragma unroll
    for (int kk = 0; kk < 16; kk++) {
      float4 av = *(const float4*)&sA[kk][tr * 4];
      float4 bv = *(const float4*)&sB[kk][tc * 4];
      const float aq[4] = {av.x, av.y, av.z, av.w};
      const float bp[4] = {bv.x, bv.y, bv.z, bv.w};
      #pragma unroll
      for (int q = 0; q < 4; q++)
        #pragma unroll
        for (int p = 0; p < 4; p++) acc[q][p] = fmaf(aq[q], bp[p], acc[q][p]);
    }
  }
  #pragma unroll
  for (int q = 0; q < 4; q++) {
    float4 v = make_float4(acc[q][0], acc[q][1], acc[q][2], acc[q][3]);
    *(float4*)&C[(size_t)(row0 + tr * 4 + q) * 256 + col0 + tc * 4] = v;
  }
  // transpose tile -> Vt[col0+d][row0+j] fp16
  #pragma unroll
  for (int q = 0; q < 4; q++)
    #pragma unroll
    for (int p = 0; p < 4; p++)
      sT[tc * 4 + p][tr * 4 + q] = (_Float16)acc[q][p];
  __syncthreads();
  const int r2 = t >> 2, s2 = t & 3;
  f16x8 w0, w1;
  #pragma unroll
  for (int k = 0; k < 8; k++) { w0[k] = sT[r2][s2 * 16 + k]; w1[k] = sT[r2][s2 * 16 + 8 + k]; }
  _Float16* dst = Vt + (size_t)(col0 + r2) * NN + row0 + s2 * 16;
  *(f16x8*)dst = w0;
  *((f16x8*)dst + 1) = w1;
}

// ---------------- Kernel 2: ui_t[h][n], uj_t[h][n] -------------------------
__global__ __launch_bounds__(256) void calc_uij(const float* __restrict__ Wh,
                                                const float* __restrict__ a,
                                                float* __restrict__ uit,
                                                float* __restrict__ ujt) {
  const int lane = threadIdx.x & 63;
  const int n = blockIdx.x * 4 + (threadIdx.x >> 6);
  #pragma unroll
  for (int h = 0; h < 4; h++) {
    float v = Wh[(size_t)n * 256 + h * 64 + lane];
    float pi = v * a[h * 128 + lane];
    float pj = v * a[h * 128 + 64 + lane];
    #pragma unroll
    for (int m = 32; m >= 1; m >>= 1) {
      pi += __shfl_xor(pi, m, 64);
      pj += __shfl_xor(pj, m, 64);
    }
    if (lane == 0) {
      uit[(size_t)h * NN + n] = __expf(0.2f * pi);
      ujt[(size_t)h * NN + n] = __expf(0.2f * pj);
    }
  }
}

// ---------------- Kernel 3: fused masked-softmax attention (MFMA) ----------
// grid (128 i-tiles of 32, CH j-chunks), block 256 = 4 waves (wave = head).
// Wave computes C[32i x 64d] = 2(it) x 4(dt) mfma_f32_16x16x32_f16 frags.
// Partials: P[((c*4+h)*4096 + i)*64 + d], L[(c*4+h)*4096 + i].
__global__ __launch_bounds__(256, 4) void gat_attn(const float* __restrict__ bias,
                                                   const _Float16* __restrict__ Vt,
                                                   const float* __restrict__ uit,
                                                   const float* __restrict__ ujt,
                                                   float* __restrict__ P,
                                                   float* __restrict__ L,
                                                   int jpc) {
  __shared__ _Float16 seb[2][32][136];   // exp(bias), [i][j] fp16, pad 8
  __shared__ float suj[2][4][128];
  const int itile = blockIdx.x;
  const int chunk = blockIdx.y;
  const int tid = threadIdx.x;
  const int lane = tid & 63;
  const int h = __builtin_amdgcn_readfirstlane(tid >> 6);
  const int m = lane & 15;
  const int quad = lane >> 4;
  const int i0 = itile * 32;
  const int j0 = chunk * jpc;
  const int nc = jpc >> 7;               // 128-j chunks

  f32x4 acc[2][4];
  #pragma unroll
  for (int it = 0; it < 2; it++)
    #pragma unroll
    for (int dt = 0; dt < 4; dt++)
      #pragma unroll
      for (int r = 0; r < 4; r++) acc[it][dt][r] = 0.f;
  float l0 = 0.f, l1 = 0.f;
  const float uiv0 = uit[(size_t)h * NN + i0 + m];
  const float uiv1 = uit[(size_t)h * NN + i0 + 16 + m];

  // ---- staging: 32 x 128 exp(bias) tile + 128 uj values per head ----
  auto stage = [&](int jc, int buf) {
    const int r = tid >> 3;              // 0..31
    const int c0 = (tid & 7) * 16;       // 0..112
    const float* bp = bias + (size_t)(i0 + r) * NN + j0 + jc * 128 + c0;
    float g[16];
    #pragma unroll
    for (int q = 0; q < 4; q++) {
      float4 v = *(const float4*)(bp + q * 4);
      g[q * 4 + 0] = v.x; g[q * 4 + 1] = v.y; g[q * 4 + 2] = v.z; g[q * 4 + 3] = v.w;
    }
    f16x8 e0, e1;
    #pragma unroll
    for (int k = 0; k < 8; k++) {
      e0[k] = (_Float16)((g[k] == 0.f) ? 0.f : __expf(g[k]));
      e1[k] = (_Float16)((g[8 + k] == 0.f) ? 0.f : __expf(g[8 + k]));
    }
    *(f16x8*)&seb[buf][r][c0] = e0;
    *(f16x8*)&seb[buf][r][c0 + 8] = e1;
    const float* up = ujt + (size_t)h * NN + j0 + jc * 128;
    suj[buf][h][lane] = up[lane];
    suj[buf][h][lane + 64] = up[lane + 64];
  };

  stage(0, 0);
  for (int jc = 0; jc < nc; jc++) {
    const int buf = jc & 1;
    __syncthreads();
    if (jc + 1 < nc) stage(jc + 1, buf ^ 1);
    #pragma unroll
    for (int s = 0; s < 4; s++) {
      const int kbase = s * 32 + quad * 8;
      // B fragments (global, L2-resident)
      const _Float16* vb = Vt + (size_t)(h * 64 + m) * NN + j0 + jc * 128 + kbase;
      f16x8 b0 = *(const f16x8*)(vb);
      f16x8 b1 = *(const f16x8*)(vb + (size_t)16 * NN);
      f16x8 b2 = *(const f16x8*)(vb + (size_t)32 * NN);
      f16x8 b3 = *(const f16x8*)(vb + (size_t)48 * NN);
      // A fragments: generate w in-register
      float4 u0 = *(const float4*)&suj[buf][h][kbase];
      float4 u1 = *(const float4*)&suj[buf][h][kbase + 4];
      const float uja[8] = {u0.x, u0.y, u0.z, u0.w, u1.x, u1.y, u1.z, u1.w};
      f16x8 e0 = *(const f16x8*)&seb[buf][m][kbase];
      f16x8 e1 = *(const f16x8*)&seb[buf][m + 16][kbase];
      f16x8 a0, a1;
      #pragma unroll
      for (int j = 0; j < 8; j++) {
        {
          float tt = uiv0 * uja[j];
          float p1 = (float)e0[j] * tt;
          float t2 = tt * tt;
          float p5 = p1 * t2 * t2;
          float w = (tt > 1.f) ? p5 : p1;
          _Float16 wh = (_Float16)w;
          a0[j] = wh; l0 += (float)wh;
        }
        {
          float tt = uiv1 * uja[j];
          float p1 = (float)e1[j] * tt;
          float t2 = tt * tt;
          float p5 = p1 * t2 * t2;
          float w = (tt > 1.f) ? p5 : p1;
          _Float16 wh = (_Float16)w;
          a1[j] = wh; l1 += (float)wh;
        }
      }
      acc[0][0] = __builtin_amdgcn_mfma_f32_16x16x32_f16(a0, b0, acc[0][0], 0, 0, 0);
      acc[0][1] = __builtin_amdgcn_mfma_f32_16x16x32_f16(a0, b1, acc[0][1], 0, 0, 0);
      acc[0][2] = __builtin_amdgcn_mfma_f32_16x16x32_f16(a0, b2, acc[0][2], 0, 0, 0);
      acc[0][3] = __builtin_amdgcn_mfma_f32_16x16x32_f16(a0, b3, acc[0][3], 0, 0, 0);
      acc[1][0] = __builtin_amdgcn_mfma_f32_16x16x32_f16(a1, b0, acc[1][0], 0, 0, 0);
      acc[1][1] = __builtin_amdgcn_mfma_f32_16x16x32_f16(a1, b1, acc[1][1], 0, 0, 0);
      acc[1][2] = __builtin_amdgcn_mfma_f32_16x16x32_f16(a1, b2, acc[1][2], 0, 0, 0);
      acc[1][3] = __builtin_amdgcn_mfma_f32_16x16x32_f16(a1, b3, acc[1][3], 0, 0, 0);
    }
  }

  // ---- epilogue: partial sums out ----
  l0 += __shfl_xor(l0, 16, 64); l0 += __shfl_xor(l0, 32, 64);
  l1 += __shfl_xor(l1, 16, 64); l1 += __shfl_xor(l1, 32, 64);
  const size_t lb = (size_t)(chunk * 4 + h) * NN + i0;
  if (lane < 16) { L[lb + m] = l0; L[lb + 16 + m] = l1; }
  const size_t pbase = ((size_t)(chunk * 4 + h) * NN + i0) * 64;
  #pragma unroll
  for (int it = 0; it < 2; it++)
    #pragma unroll
    for (int dt = 0; dt < 4; dt++)
      #pragma unroll
      for (int r = 0; r < 4; r++) {
        const int irow = it * 16 + quad * 4 + r;
        const int d = dt * 16 + m;
        P[pbase + (size_t)irow * 64 + d] = acc[it][dt][r];
      }
}

// ---------------- Kernel 4: reduce, normalize, ELU -------------------------
__global__ __launch_bounds__(256) void reduce_out(const float* __restrict__ P,
                                                  const float* __restrict__ L,
                                                  const float* __restrict__ Wh,
                                                  float* __restrict__ out,
                                                  int CH) {
  const int i0 = blockIdx.x * 64;
  const int h = blockIdx.y;
  const int t = threadIdx.x;
  const int d = t & 63;
  const int isub = t >> 6;
  for (int ii = 0; ii < 16; ii++) {
    const int i = i0 + isub * 16 + ii;
    float lsum = 0.f, s = 0.f;
    for (int c = 0; c < CH; c++) {
      lsum += L[(size_t)(c * 4 + h) * NN + i];
      s += P[((size_t)(c * 4 + h) * NN + i) * 64 + d];
    }
    const float wh = Wh[(size_t)i * 256 + h * 64 + d];
    const bool fb = (lsum == 0.f);
    float o = fb ? wh : s / lsum;
    o = (o > 0.f) ? o : (__expf(o) - 1.f);
    out[(size_t)i * 256 + h * 64 + d] = o;
  }
}

extern "C" void kernel_launch(void* const* d_in, const int* in_sizes, int n_in,
                              void* d_out, int out_size, void* d_ws, size_t ws_size,
                              hipStream_t stream) {
  const float* h_in = (const float*)d_in[0];   // (4096, 256)
  const float* adj  = (const float*)d_in[1];   // (4096, 4096)
  const float* W    = (const float*)d_in[2];   // (256, 256)
  const float* a    = (const float*)d_in[3];   // (4, 128)
  float* out = (float*)d_out;
  float* ws = (float*)d_ws;

  int CH = 8;
  while (CH > 1) {
    size_t floats = 1048576 /*Wh*/ + 524288 /*Vt*/ + 32768 /*ui,uj*/ +
                    (size_t)CH * 16384 /*L*/ + (size_t)CH * 1048576 /*P*/;
    if (floats * 4 <= ws_size) break;
    CH >>= 1;
  }
  const int jpc = NN / CH;

  float* Wh = ws;
  _Float16* Vt = (_Float16*)(ws + 1048576);
  float* uit = ws + 1048576 + 524288;
  float* ujt = uit + 16384;
  float* Lb = ujt + 16384;
  float* Pb = Lb + (size_t)CH * 16384;

  hipLaunchKernelGGL(gemm_wh, dim3(4, 64), dim3(256), 0, stream, h_in, W, Wh, Vt);
  hipLaunchKernelGGL(calc_uij, dim3(1024), dim3(256), 0, stream, Wh, a, uit, ujt);
  hipLaunchKernelGGL(gat_attn, dim3(128, CH), dim3(256), 0, stream,
                     adj, Vt, uit, ujt, Pb, Lb, jpc);
  hipLaunchKernelGGL(reduce_out, dim3(64, 4), dim3(256), 0, stream,
                     Pb, Lb, Wh, out, CH);
}

// Round 4
// 155.019 us; speedup vs baseline: 2.4197x; 1.2568x over previous
//
#include <hip/hip_runtime.h>
#include <cstdint>
#include <cstddef>

// DenseGAT, N=4096, IN_DIM=256, H=4, D=64, NEG_SLOPE=0.2
// w[i,j,h] = eb * max(t5, tt);  tt = ui*uj = exp(.2(ei+ej)),
//   t5 = ui5*uj5 = exp(ei+ej) = tt^5 (exact inputs), eb = exp(bias) or 0.
// max trick: tt>1 => t5>tt, tt<1 => t5<tt, so select == max. Row sums via
// an extra MFMA against a ones-B fragment (no serial VALU add chain).

typedef _Float16 f16x4 __attribute__((ext_vector_type(4)));
typedef _Float16 f16x8 __attribute__((ext_vector_type(8)));
typedef float f32x4 __attribute__((ext_vector_type(4)));

#define NN 4096

// ---- Kernel 1: Wh = h @ W (fp32) + Vt (fp16 transpose) + ui/uj exps ------
// grid (4 heads, 128 row-tiles of 32), block 256.
__global__ __launch_bounds__(256) void gemm_wh(
    const float* __restrict__ A, const float* __restrict__ Bw,
    const float* __restrict__ av, float* __restrict__ C,
    _Float16* __restrict__ Vt,
    _Float16* __restrict__ uit, _Float16* __restrict__ ui5t,
    _Float16* __restrict__ ujt, _Float16* __restrict__ uj5t) {
  __shared__ float sA[32][36];      // [k][row]
  __shared__ float sB[32][68];      // [k][col]
  __shared__ _Float16 sT[64][40];   // transpose staging
  const int h  = blockIdx.x;
  const int by = blockIdx.y;
  const int t  = threadIdx.x;
  const int row0 = by * 32, col0 = h * 64;
  const int tc = t & 15, tr = t >> 4;      // cols tc*4..+3, rows tr*2..+1
  float acc[2][4];
  #pragma unroll
  for (int q = 0; q < 2; q++)
    #pragma unroll
    for (int p = 0; p < 4; p++) acc[q][p] = 0.f;

  for (int k0 = 0; k0 < 256; k0 += 32) {
    __syncthreads();
    {
      const int r = t >> 3, k4 = (t & 7) * 4;      // A: 32x32
      float4 v = *(const float4*)&A[(size_t)(row0 + r) * 256 + k0 + k4];
      sA[k4 + 0][r] = v.x; sA[k4 + 1][r] = v.y;
      sA[k4 + 2][r] = v.z; sA[k4 + 3][r] = v.w;
    }
    #pragma unroll
    for (int q = 0; q < 2; q++) {                   // B: 32x64
      const int u = t + q * 256;
      const int kr = u >> 4, c4 = (u & 15) * 4;
      *(float4*)&sB[kr][c4] =
          *(const float4*)&Bw[(size_t)(k0 + kr) * 256 + col0 + c4];
    }
    __syncthreads();
    #pragma unroll
    for (int kk = 0; kk < 32; kk++) {
      float2 a2 = *(const float2*)&sA[kk][tr * 2];
      float4 bv = *(const float4*)&sB[kk][tc * 4];
      const float bp[4] = {bv.x, bv.y, bv.z, bv.w};
      #pragma unroll
      for (int p = 0; p < 4; p++) {
        acc[0][p] = fmaf(a2.x, bp[p], acc[0][p]);
        acc[1][p] = fmaf(a2.y, bp[p], acc[1][p]);
      }
    }
  }
  // C store (fp32 Wh)
  #pragma unroll
  for (int q = 0; q < 2; q++) {
    float4 v = make_float4(acc[q][0], acc[q][1], acc[q][2], acc[q][3]);
    *(float4*)&C[(size_t)(row0 + tr * 2 + q) * 256 + col0 + tc * 4] = v;
  }
  // ei/ej: dot with a_i, a_j over the 64 cols of this head
  {
    float pi[2] = {0.f, 0.f}, pj[2] = {0.f, 0.f};
    #pragma unroll
    for (int q = 0; q < 2; q++)
      #pragma unroll
      for (int p = 0; p < 4; p++) {
        const int d = tc * 4 + p;
        pi[q] = fmaf(acc[q][p], av[h * 128 + d], pi[q]);
        pj[q] = fmaf(acc[q][p], av[h * 128 + 64 + d], pj[q]);
      }
    #pragma unroll
    for (int m = 1; m <= 8; m <<= 1) {
      #pragma unroll
      for (int q = 0; q < 2; q++) {
        pi[q] += __shfl_xor(pi[q], m, 64);
        pj[q] += __shfl_xor(pj[q], m, 64);
      }
    }
    if (tc == 0) {
      #pragma unroll
      for (int q = 0; q < 2; q++) {
        const int row = row0 + tr * 2 + q;
        uit [(size_t)h * NN + row] = (_Float16)__expf(0.2f * pi[q]);
        ui5t[(size_t)h * NN + row] = (_Float16)__expf(pi[q]);       // = ui^5
        ujt [(size_t)h * NN + row] = (_Float16)__expf(0.2f * pj[q]);
        uj5t[(size_t)h * NN + row] = (_Float16)__expf(pj[q]);       // = uj^5
      }
    }
  }
  // Vt transpose: Vt[col0+d][row0+j] fp16
  #pragma unroll
  for (int q = 0; q < 2; q++)
    #pragma unroll
    for (int p = 0; p < 4; p++)
      sT[tc * 4 + p][tr * 2 + q] = (_Float16)acc[q][p];
  __syncthreads();
  {
    const int dd = t >> 2, j8 = (t & 3) * 8;
    f16x8 w;
    #pragma unroll
    for (int k = 0; k < 8; k++) w[k] = sT[dd][j8 + k];
    *(f16x8*)&Vt[(size_t)(col0 + dd) * NN + row0 + j8] = w;
  }
}

// ---- Kernel 2: fused masked-softmax attention (MFMA) ---------------------
// grid (128 i-tiles of 32, CH j-chunks), block 256 = 4 waves (wave = head).
__global__ __launch_bounds__(256, 4) void gat_attn(
    const float* __restrict__ bias, const _Float16* __restrict__ Vt,
    const _Float16* __restrict__ uit, const _Float16* __restrict__ ui5t,
    const _Float16* __restrict__ ujt, const _Float16* __restrict__ uj5t,
    float* __restrict__ P, float* __restrict__ L, int jpc) {
  __shared__ _Float16 seb[2][32][136];   // exp(bias) tile [i][j], pad 8
  const int itile = blockIdx.x;
  const int chunk = blockIdx.y;
  const int tid = threadIdx.x;
  const int lane = tid & 63;
  const int h = __builtin_amdgcn_readfirstlane(tid >> 6);
  const int m = lane & 15;
  const int quad = lane >> 4;
  const int i0 = itile * 32;
  const int j0 = chunk * jpc;
  const int nc = jpc >> 7;

  f32x4 acc[2][5];                       // [it][dt0..3, ones-col]
  #pragma unroll
  for (int it = 0; it < 2; it++)
    #pragma unroll
    for (int dt = 0; dt < 5; dt++)
      #pragma unroll
      for (int r = 0; r < 4; r++) acc[it][dt][r] = 0.f;

  const _Float16 ui_0 = uit [(size_t)h * NN + i0 + m];
  const _Float16 ui_1 = uit [(size_t)h * NN + i0 + 16 + m];
  const _Float16 u5_0 = ui5t[(size_t)h * NN + i0 + m];
  const _Float16 u5_1 = ui5t[(size_t)h * NN + i0 + 16 + m];
  const f16x8 ui8_0 = {ui_0, ui_0, ui_0, ui_0, ui_0, ui_0, ui_0, ui_0};
  const f16x8 ui8_1 = {ui_1, ui_1, ui_1, ui_1, ui_1, ui_1, ui_1, ui_1};
  const f16x8 u58_0 = {u5_0, u5_0, u5_0, u5_0, u5_0, u5_0, u5_0, u5_0};
  const f16x8 u58_1 = {u5_1, u5_1, u5_1, u5_1, u5_1, u5_1, u5_1, u5_1};
  const f16x8 kOne = {(_Float16)1.f, (_Float16)1.f, (_Float16)1.f, (_Float16)1.f,
                      (_Float16)1.f, (_Float16)1.f, (_Float16)1.f, (_Float16)1.f};

  auto stage = [&](int jc, int buf) {
    const int r = tid >> 3, f = tid & 7;
    const float* bp = bias + (size_t)(i0 + r) * NN + j0 + jc * 128;
    #pragma unroll
    for (int q = 0; q < 4; q++) {
      float4 v = *(const float4*)(bp + f * 4 + q * 32);
      f16x4 e;
      e[0] = (_Float16)((v.x == 0.f) ? 0.f : __expf(v.x));
      e[1] = (_Float16)((v.y == 0.f) ? 0.f : __expf(v.y));
      e[2] = (_Float16)((v.z == 0.f) ? 0.f : __expf(v.z));
      e[3] = (_Float16)((v.w == 0.f) ? 0.f : __expf(v.w));
      *(f16x4*)&seb[buf][r][f * 4 + q * 32] = e;
    }
  };

  stage(0, 0);
  for (int jc = 0; jc < nc; jc++) {
    const int buf = jc & 1;
    __syncthreads();
    if (jc + 1 < nc) stage(jc + 1, buf ^ 1);

    const _Float16* vb  = Vt + (size_t)(h * 64 + m) * NN + j0 + jc * 128 + quad * 8;
    const _Float16* ujb = ujt  + (size_t)h * NN + j0 + jc * 128 + quad * 8;
    const _Float16* u5b = uj5t + (size_t)h * NN + j0 + jc * 128 + quad * 8;

    f16x8 bc[4], bn[4];
    #pragma unroll
    for (int dt = 0; dt < 4; dt++)
      bc[dt] = *(const f16x8*)(vb + (size_t)(dt * 16) * NN);

    #pragma unroll
    for (int s = 0; s < 4; s++) {
      if (s < 3) {
        #pragma unroll
        for (int dt = 0; dt < 4; dt++)
          bn[dt] = *(const f16x8*)(vb + (size_t)(dt * 16) * NN + (s + 1) * 32);
      }
      const f16x8 uj8  = *(const f16x8*)(ujb + s * 32);
      const f16x8 uj58 = *(const f16x8*)(u5b + s * 32);
      const f16x8 e0 = *(const f16x8*)&seb[buf][m][s * 32 + quad * 8];
      const f16x8 e1 = *(const f16x8*)&seb[buf][m + 16][s * 32 + quad * 8];
      // w = eb * max(ui5*uj5, ui*uj)  — packed f16, whole-vector ops
      const f16x8 a0 = e0 * __builtin_elementwise_max(u58_0 * uj58, ui8_0 * uj8);
      const f16x8 a1 = e1 * __builtin_elementwise_max(u58_1 * uj58, ui8_1 * uj8);
      #pragma unroll
      for (int dt = 0; dt < 4; dt++) {
        acc[0][dt] = __builtin_amdgcn_mfma_f32_16x16x32_f16(a0, bc[dt], acc[0][dt], 0, 0, 0);
        acc[1][dt] = __builtin_amdgcn_mfma_f32_16x16x32_f16(a1, bc[dt], acc[1][dt], 0, 0, 0);
      }
      acc[0][4] = __builtin_amdgcn_mfma_f32_16x16x32_f16(a0, kOne, acc[0][4], 0, 0, 0);
      acc[1][4] = __builtin_amdgcn_mfma_f32_16x16x32_f16(a1, kOne, acc[1][4], 0, 0, 0);
      if (s < 3) {
        #pragma unroll
        for (int dt = 0; dt < 4; dt++) bc[dt] = bn[dt];
      }
    }
  }

  // epilogue: partials
  const size_t lb = (size_t)(chunk * 4 + h) * NN + i0;
  if (m == 0) {
    #pragma unroll
    for (int it = 0; it < 2; it++)
      #pragma unroll
      for (int r = 0; r < 4; r++)
        L[lb + it * 16 + quad * 4 + r] = acc[it][4][r];
  }
  const size_t pbase = ((size_t)(chunk * 4 + h) * NN + i0) * 64;
  #pragma unroll
  for (int it = 0; it < 2; it++)
    #pragma unroll
    for (int dt = 0; dt < 4; dt++)
      #pragma unroll
      for (int r = 0; r < 4; r++)
        P[pbase + (size_t)(it * 16 + quad * 4 + r) * 64 + dt * 16 + m] = acc[it][dt][r];
}

// ---- Kernel 3: reduce partials, normalize, ELU ---------------------------
// grid (256 i-tiles of 16, 4 heads), block 256.
template <int CHT>
__global__ __launch_bounds__(256) void reduce_out(
    const float* __restrict__ P, const float* __restrict__ L,
    const float* __restrict__ Wh, float* __restrict__ out) {
  const int i0 = blockIdx.x * 16;
  const int h = blockIdx.y;
  const int t = threadIdx.x;
  const int d = t & 63;
  const int isub = t >> 6;
  #pragma unroll
  for (int ii = 0; ii < 4; ii++) {
    const int i = i0 + isub * 4 + ii;
    float lsum = 0.f, s = 0.f;
    #pragma unroll
    for (int c = 0; c < CHT; c++) {
      lsum += L[(size_t)(c * 4 + h) * NN + i];
      s += P[((size_t)(c * 4 + h) * NN + i) * 64 + d];
    }
    const float wh = Wh[(size_t)i * 256 + h * 64 + d];
    const bool fb = (lsum == 0.f);
    float o = fb ? wh : s / lsum;
    o = (o > 0.f) ? o : (__expf(o) - 1.f);
    out[(size_t)i * 256 + h * 64 + d] = o;
  }
}

extern "C" void kernel_launch(void* const* d_in, const int* in_sizes, int n_in,
                              void* d_out, int out_size, void* d_ws, size_t ws_size,
                              hipStream_t stream) {
  const float* h_in = (const float*)d_in[0];   // (4096, 256)
  const float* adj  = (const float*)d_in[1];   // (4096, 4096)
  const float* W    = (const float*)d_in[2];   // (256, 256)
  const float* a    = (const float*)d_in[3];   // (4, 128)
  float* out = (float*)d_out;
  float* ws = (float*)d_ws;

  int CH = 8;
  while (CH > 1) {
    size_t floats = 1048576 /*Wh*/ + 524288 /*Vt f16*/ + 32768 /*u arrays*/ +
                    (size_t)CH * (16384 + 1048576);
    if (floats * 4 <= ws_size) break;
    CH >>= 1;
  }
  const int jpc = NN / CH;

  float* Wh = ws;
  _Float16* Vt   = (_Float16*)(ws + 1048576);
  _Float16* uit  = (_Float16*)(ws + 1048576 + 524288);
  _Float16* ui5t = uit + 16384;
  _Float16* ujt  = ui5t + 16384;
  _Float16* uj5t = ujt + 16384;
  float* Lb = ws + 1048576 + 524288 + 32768;
  float* Pb = Lb + (size_t)CH * 16384;

  hipLaunchKernelGGL(gemm_wh, dim3(4, 128), dim3(256), 0, stream,
                     h_in, W, a, Wh, Vt, uit, ui5t, ujt, uj5t);
  hipLaunchKernelGGL(gat_attn, dim3(128, CH), dim3(256), 0, stream,
                     adj, Vt, uit, ui5t, ujt, uj5t, Pb, Lb, jpc);
  switch (CH) {
    case 8: hipLaunchKernelGGL((reduce_out<8>), dim3(256, 4), dim3(256), 0, stream, Pb, Lb, Wh, out); break;
    case 4: hipLaunchKernelGGL((reduce_out<4>), dim3(256, 4), dim3(256), 0, stream, Pb, Lb, Wh, out); break;
    case 2: hipLaunchKernelGGL((reduce_out<2>), dim3(256, 4), dim3(256), 0, stream, Pb, Lb, Wh, out); break;
    default: hipLaunchKernelGGL((reduce_out<1>), dim3(256, 4), dim3(256), 0, stream, Pb, Lb, Wh, out); break;
  }
}